// Round 6
// baseline (1143.701 us; speedup 1.0000x reference)
//
#include <hip/hip_runtime.h>

// Problem constants (from reference)
#define NBATCH 256
#define LI 2
#define LH 150
#define LQ 10
#define HS 128
#define WSD 128
#define KIT 40
#define AOUT 5

// LDS plane: 128x128 interior + 1-pixel zero halo, width padded to 132.
// Interior pixel (y,x) lives at plane[(y+1)*LCOLS + (x+1)].
#define LROWS 130
#define LCOLS 132
#define PLANE (LROWS * LCOLS)

// ---- Prep: collapse the linear hidden layer.
// W_eff[i,ky,kx] = sum_h r_w[h]*h_w[h,i,ky,kx],  b_eff = sum_h r_w[h]*h_b[h].
__global__ void prep_weff(const float* __restrict__ h_w,
                          const float* __restrict__ h_b,
                          const float* __restrict__ r_w,
                          float* __restrict__ w_eff) {
  const int t = threadIdx.x;
  if (t < 18) {
    const int i = t / 9, k = t % 9;
    double s = 0.0;
    for (int h = 0; h < LH; ++h)
      s += (double)r_w[h] * (double)h_w[(h * LI + i) * 9 + k];
    w_eff[t] = (float)s;
  } else if (t == 18) {
    double s = 0.0;
    for (int h = 0; h < LH; ++h)
      s += (double)r_w[h] * (double)h_b[h];
    w_eff[18] = (float)s;
  }
}

// Load a 6-wide row (16B-aligned base) with vectorized LDS reads.
__device__ __forceinline__ void load_row6(const float* __restrict__ p, float row[6]) {
  const float4 a = *reinterpret_cast<const float4*>(p);
  const float2 b = *reinterpret_cast<const float2*>(p + 4);
  row[0] = a.x; row[1] = a.y; row[2] = a.z; row[3] = a.w;
  row[4] = b.x; row[5] = b.y;
}

// SROA RULE (rounds 1-4 lesson): local arrays must only ever be indexed by
// compile-time literals; the dy dimension is hand-unrolled via macros.
// Violations demote arrays to scratch: 66 MB writeback, ~3x VALU inflation.

// One VI row: outv[DY][*] = max_c [ conv(r,q_c) + conv(v,w_c) ] using the
// persistent register r-neighborhood nbr[6][6] and rolling vwin[3][6]
// (= v rows DY..DY+2 of the 6-row window). All indices literal.
#define VI_ROW(DY)                                                         \
  {                                                                        \
    _Pragma("unroll")                                                      \
    for (int dx = 0; dx < 4; ++dx) outv[DY][dx] = -__builtin_inff();       \
    _Pragma("unroll 2")                                                    \
    for (int c = 0; c < LQ; ++c) {                                         \
      const float* qc = q_w + c * 9;                                       \
      const float* wc = w_in + c * 9;                                      \
      float acc[4];                                                        \
      _Pragma("unroll")                                                    \
      for (int dx = 0; dx < 4; ++dx)                                       \
        acc[dx] = qc[0] * nbr[DY][dx] + wc[0] * vwin[0][dx];               \
      _Pragma("unroll")                                                    \
      for (int kk = 1; kk < 9; ++kk) {                                     \
        const int ky = kk / 3, kx = kk % 3;                                \
        const float qv_ = qc[kk];                                          \
        const float wv_ = wc[kk];                                          \
        _Pragma("unroll")                                                  \
        for (int dx = 0; dx < 4; ++dx)                                     \
          acc[dx] += qv_ * nbr[DY + ky][dx + kx] + wv_ * vwin[ky][dx + kx];\
      }                                                                    \
      _Pragma("unroll")                                                    \
      for (int dx = 0; dx < 4; ++dx)                                       \
        outv[DY][dx] = fmaxf(outv[DY][dx], acc[dx]);                       \
    }                                                                      \
  }

// Shift the v-window down one row and load plane row NEXTROW into slot 2.
#define VSHIFT(NEXTROW)                                                    \
  {                                                                        \
    _Pragma("unroll")                                                      \
    for (int j = 0; j < 6; ++j) {                                          \
      vwin[0][j] = vwin[1][j]; vwin[1][j] = vwin[2][j];                    \
    }                                                                      \
    load_row6(vp + (NEXTROW) * LCOLS, vwin[2]);                            \
  }

// r-phase: shift both input windows, load next rows.
#define WIN_SHIFT2(NEXTROW)                                                \
  {                                                                        \
    _Pragma("unroll")                                                      \
    for (int j = 0; j < 6; ++j) {                                          \
      rwin[0][j] = rwin[1][j]; rwin[1][j] = rwin[2][j];                    \
      vwin[0][j] = vwin[1][j]; vwin[1][j] = vwin[2][j];                    \
    }                                                                      \
    load_row6(rp + (NEXTROW) * LCOLS, rwin[2]);                            \
    load_row6(vp + (NEXTROW) * LCOLS, vwin[2]);                            \
  }

// One r-phase row: racc[DY][*] = b_eff + W_eff(ch0)*rwin + W_eff(ch1)*vwin.
#define R_ROW(DY)                                                          \
  {                                                                        \
    _Pragma("unroll")                                                      \
    for (int dx = 0; dx < 4; ++dx) racc[DY][dx] = beff;                    \
    _Pragma("unroll")                                                      \
    for (int kk = 0; kk < 9; ++kk) {                                       \
      const int ky = kk / 3, kx = kk % 3;                                  \
      const float w0 = w_eff[kk];                                          \
      const float w1 = w_eff[9 + kk];                                      \
      _Pragma("unroll")                                                    \
      for (int dx = 0; dx < 4; ++dx)                                       \
        racc[DY][dx] += w0 * rwin[ky][dx + kx] + w1 * vwin[ky][dx + kx];   \
    }                                                                      \
  }

// One block per batch item; 1024 threads; each thread owns a 4x4 tile.
// LDS: two ping-pong v planes (137 KB) -> 1 block/CU, 16 waves (4/SIMD).
// r lives entirely in registers (nbr[6][6]); one barrier per VI iteration.
// Peak regs: nbr 36 + vwin 18 + outv 16 + acc 4 + misc ~ 95 < 128 budget.
__global__ __launch_bounds__(1024)
__attribute__((amdgpu_waves_per_eu(4, 4)))
void vin_main(const float* __restrict__ input,
              const int* __restrict__ coords,
              const float* __restrict__ q_w,
              const float* __restrict__ w_in,
              const float* __restrict__ fc_w,
              const float* __restrict__ w_eff,
              float* __restrict__ out) {
  extern __shared__ float lds[];
  float* p0 = lds;           // stages ch0; then v ping-pong plane 0
  float* p1 = lds + PLANE;   // stages ch1; then r (briefly); then v plane 1

  const int b = blockIdx.x;
  const int tid = threadIdx.x;
  const int ty = tid >> 5;             // 0..31
  const int tx = tid & 31;             // 0..31
  const int y0 = ty << 2;              // output rows y0..y0+3
  const int x0 = tx << 2;              // output cols x0..x0+3
  const int nb_off = y0 * LCOLS + x0;  // 6x6 window top-left (16B-aligned)
  const int wbase = (y0 + 1) * LCOLS + (x0 + 1);  // interior write base

  // zero both planes (establishes the zero halo)
  for (int i = tid; i < 2 * PLANE; i += 1024) lds[i] = 0.0f;
  __syncthreads();

  // stage input: ch0 -> p0 interior, ch1 -> p1 interior (float4 global loads)
  const float* in0 = input + (size_t)b * (LI * HS * WSD);
  const float* in1 = in0 + HS * WSD;
  {
    const float4* in40 = (const float4*)in0;
    const float4* in41 = (const float4*)in1;
    for (int i = tid; i < HS * WSD / 4; i += 1024) {
      const int y = i >> 5, x4 = (i & 31) << 2;
      const float4 a = in40[i];
      const float4 c = in41[i];
      float* r0 = p0 + (y + 1) * LCOLS + (x4 + 1);
      float* v0 = p1 + (y + 1) * LCOLS + (x4 + 1);
      r0[0] = a.x; r0[1] = a.y; r0[2] = a.z; r0[3] = a.w;
      v0[0] = c.x; v0[1] = c.y; v0[2] = c.z; v0[3] = c.w;
    }
  }
  __syncthreads();

  // ---- r = conv(input, W_eff, pad=1) + b_eff  (rolling windows) ----
  {
    const float* rp = p0 + nb_off;
    const float* vp = p1 + nb_off;
    float rwin[3][6], vwin[3][6], racc[4][4];
    load_row6(rp, rwin[0]); load_row6(rp + LCOLS, rwin[1]); load_row6(rp + 2 * LCOLS, rwin[2]);
    load_row6(vp, vwin[0]); load_row6(vp + LCOLS, vwin[1]); load_row6(vp + 2 * LCOLS, vwin[2]);
    const float beff = w_eff[18];
    R_ROW(0) WIN_SHIFT2(3) R_ROW(1) WIN_SHIFT2(4) R_ROW(2) WIN_SHIFT2(5) R_ROW(3)
    __syncthreads();  // all input-window reads done before overwriting
    // p1 <- r (for the one-time nbr exchange), p0 <- 0 (v starts at zero)
#pragma unroll
    for (int dy = 0; dy < 4; ++dy) {
      float* rw = p1 + wbase + dy * LCOLS;
      float* zw = p0 + wbase + dy * LCOLS;
      rw[0] = racc[dy][0]; rw[1] = racc[dy][1]; rw[2] = racc[dy][2]; rw[3] = racc[dy][3];
      zw[0] = 0.0f; zw[1] = 0.0f; zw[2] = 0.0f; zw[3] = 0.0f;
    }
  }
  __syncthreads();

  // one-time halo exchange: r 6x6 neighborhood -> persistent registers
  float nbr[6][6];
  {
    const float* rp = p1 + nb_off;
    load_row6(rp,             nbr[0]);
    load_row6(rp + 1 * LCOLS, nbr[1]);
    load_row6(rp + 2 * LCOLS, nbr[2]);
    load_row6(rp + 3 * LCOLS, nbr[3]);
    load_row6(rp + 4 * LCOLS, nbr[4]);
    load_row6(rp + 5 * LCOLS, nbr[5]);
  }
  __syncthreads();  // everyone has nbr before it=0 overwrites p1

  // ---- 40 identical VI iterations, ping-pong planes, ONE barrier each ----
  // it=0 reads v==0 from p0 -> produces exactly v0 = max_c conv(r, q_w_c).
  // it even: read p0, write p1; it odd: read p1, write p0. Final v in p0.
#pragma unroll 1
  for (int it = 0; it < KIT; ++it) {
    const float* vp = lds + ((it & 1) ? PLANE : 0) + nb_off;
    float* wr = lds + ((it & 1) ? 0 : PLANE) + wbase;
    float vwin[3][6], outv[4][4];
    load_row6(vp, vwin[0]); load_row6(vp + LCOLS, vwin[1]); load_row6(vp + 2 * LCOLS, vwin[2]);
    VI_ROW(0) VSHIFT(3) VI_ROW(1) VSHIFT(4) VI_ROW(2) VSHIFT(5) VI_ROW(3)
#pragma unroll
    for (int dy = 0; dy < 4; ++dy) {
      float* vw = wr + dy * LCOLS;
      vw[0] = outv[dy][0]; vw[1] = outv[dy][1]; vw[2] = outv[dy][2]; vw[3] = outv[dy][3];
    }
    __syncthreads();  // writes visible; also orders next iter's overwrites
  }

  // ---- epilogue: q at (sx,sy) only; r recomputed from pristine global input
  if (tid == 0) {
    const int sx = coords[b * 4 + 0];  // H index
    const int sy = coords[b * 4 + 1];  // W index
    const float beff = w_eff[18];
    float rv[3][3];
#pragma unroll
    for (int ky = 0; ky < 3; ++ky)
#pragma unroll
      for (int kx = 0; kx < 3; ++kx) {
        const int yy = sx - 1 + ky, xx = sy - 1 + kx;
        float acc = 0.0f;
        if (yy >= 0 && yy < HS && xx >= 0 && xx < WSD) {
          acc = beff;
#pragma unroll
          for (int j = 0; j < 3; ++j)
#pragma unroll
            for (int i = 0; i < 3; ++i) {
              const int yi = yy - 1 + j, xi = xx - 1 + i;
              if (yi >= 0 && yi < HS && xi >= 0 && xi < WSD)
                acc += w_eff[j * 3 + i] * in0[yi * WSD + xi] +
                       w_eff[9 + j * 3 + i] * in1[yi * WSD + xi];
            }
        }
        rv[ky][kx] = acc;
      }
    const float* vb2 = p0 + sx * LCOLS + sy;  // final v plane, 3x3 window
    float qv[LQ];
#pragma unroll
    for (int c = 0; c < LQ; ++c) {
      float s = 0.0f;
#pragma unroll
      for (int kk = 0; kk < 9; ++kk) {
        const int ky = kk / 3, kx = kk % 3;
        s += q_w[c * 9 + kk] * rv[ky][kx] +
             w_in[c * 9 + kk] * vb2[ky * LCOLS + kx];
      }
      qv[c] = s;
    }
#pragma unroll
    for (int a = 0; a < AOUT; ++a) {
      float s = 0.0f;
#pragma unroll
      for (int c = 0; c < LQ; ++c) s += fc_w[a * LQ + c] * qv[c];
      out[b * AOUT + a] = s;
    }
  }
}

extern "C" void kernel_launch(void* const* d_in, const int* in_sizes, int n_in,
                              void* d_out, int out_size, void* d_ws, size_t ws_size,
                              hipStream_t stream) {
  const float* input = (const float*)d_in[0];   // (B, 2, 128, 128)
  const int*   coords = (const int*)d_in[1];    // (B, 4)
  const float* h_w = (const float*)d_in[2];     // (150, 2, 3, 3)
  const float* h_b = (const float*)d_in[3];     // (150,)
  const float* r_w = (const float*)d_in[4];     // (1, 150, 1, 1)
  const float* q_w = (const float*)d_in[5];     // (10, 1, 3, 3)
  const float* w_in = (const float*)d_in[6];    // (10, 1, 3, 3)
  const float* fc_w = (const float*)d_in[7];    // (5, 10)
  float* out = (float*)d_out;                   // (B, 5)
  float* w_eff = (float*)d_ws;                  // 19 floats scratch

  const size_t smem = (size_t)2 * PLANE * sizeof(float);  // 137,280 B (>64KB)
  hipFuncSetAttribute(reinterpret_cast<const void*>(vin_main),
                      hipFuncAttributeMaxDynamicSharedMemorySize, (int)smem);

  prep_weff<<<1, 64, 0, stream>>>(h_w, h_b, r_w, w_eff);
  vin_main<<<NBATCH, 1024, smem, stream>>>(input, coords, q_w, w_in, fc_w, w_eff, out);
}

// Round 7
// 976.440 us; speedup vs baseline: 1.1713x; 1.1713x over previous
//
#include <hip/hip_runtime.h>

// Problem constants (from reference)
#define NBATCH 256
#define LI 2
#define LH 150
#define LQ 10
#define HS 128
#define WSD 128
#define KIT 40
#define AOUT 5

// Plane layout (per plane): 130 rows x 132 cols of dwords.
//   pixel (y,x) -> plane[(y+1)*LCOLS + x]
//   row 0 = top zero halo, row 129 = bottom zero halo
//   cols 128..131 = zero right-pad; col -1 of row y aliases row y-1's col 131
//   (zero) -> serves as the LEFT halo with NO extra column, keeping every
//   access 8/16B-aligned. A 4-dword zero pre-pad before each plane absorbs
//   the (row0, x0=0) b64 read at dword -2.
#define LCOLS 132
#define LROWS 130
#define PLANE (LROWS * LCOLS)   // 17160 dwords
#define RPOFF 4                 // rplane pre-pad
#define VPOFF (RPOFF + PLANE + 4)  // 17168, mult of 8 -> alignment preserved
#define LDS_DWORDS (VPOFF + PLANE) // 34328 dwords = 137,312 B

// ---- Prep: collapse the linear hidden layer.
// W_eff[i,ky,kx] = sum_h r_w[h]*h_w[h,i,ky,kx],  b_eff = sum_h r_w[h]*h_b[h].
__global__ void prep_weff(const float* __restrict__ h_w,
                          const float* __restrict__ h_b,
                          const float* __restrict__ r_w,
                          float* __restrict__ w_eff) {
  const int t = threadIdx.x;
  if (t < 18) {
    const int i = t / 9, k = t % 9;
    double s = 0.0;
    for (int h = 0; h < LH; ++h)
      s += (double)r_w[h] * (double)h_w[(h * LI + i) * 9 + k];
    w_eff[t] = (float)s;
  } else if (t == 18) {
    double s = 0.0;
    for (int h = 0; h < LH; ++h)
      s += (double)r_w[h] * (double)h_b[h];
    w_eff[18] = (float)s;
  }
}

// SROA RULE (rounds 1-4): local arrays only ever indexed by compile-time
// literals; dy hand-unrolled via macros. VGPR WALL (rounds 2/3/6): the
// toolchain will not allocate >64 VGPRs here — total live set must stay
// under ~62 floats. Round 5 (56 VGPR, no spill) is the proven envelope.

// Load window row R of plane-window base P into W[6] (= pixel cols
// x0-1..x0+4). b64 @ -2 (8B-aligned), b128 @ 0, b64 @ +4. All aligned,
// conflict class: b128 2-way (free), b64 4-way (1.58x, 2 of 4 ops).
#define LOAD_WROW(P, R, W)                                                   \
  {                                                                          \
    const float2 a_ = *reinterpret_cast<const float2*>((P) + (R) * LCOLS - 2); \
    const float4 b_ = *reinterpret_cast<const float4*>((P) + (R) * LCOLS);     \
    const float2 c_ = *reinterpret_cast<const float2*>((P) + (R) * LCOLS + 4); \
    W[0] = a_.y; W[1] = b_.x; W[2] = b_.y; W[3] = b_.z; W[4] = b_.w;         \
    W[5] = c_.x;                                                             \
  }

// One VI row: outv[DY][*] = max_c [ conv(r,q_c) + conv(v,w_c) ] from rolling
// rwin/vwin [3][6]. All FMAs forced via __builtin_fmaf (contraction test).
#define VI_ROW(DY)                                                         \
  {                                                                        \
    _Pragma("unroll")                                                      \
    for (int dx = 0; dx < 4; ++dx) outv[DY][dx] = -__builtin_inff();       \
    _Pragma("unroll 2")                                                    \
    for (int c = 0; c < LQ; ++c) {                                         \
      const float* qc = q_w + c * 9;                                       \
      const float* wc = w_in + c * 9;                                      \
      float acc[4];                                                        \
      _Pragma("unroll")                                                    \
      for (int dx = 0; dx < 4; ++dx)                                       \
        acc[dx] = __builtin_fmaf(wc[0], vwin[0][dx], qc[0] * rwin[0][dx]); \
      _Pragma("unroll")                                                    \
      for (int kk = 1; kk < 9; ++kk) {                                     \
        const int ky = kk / 3, kx = kk % 3;                                \
        const float qv_ = qc[kk];                                          \
        const float wv_ = wc[kk];                                          \
        _Pragma("unroll")                                                  \
        for (int dx = 0; dx < 4; ++dx)                                     \
          acc[dx] = __builtin_fmaf(qv_, rwin[ky][dx + kx],                 \
                    __builtin_fmaf(wv_, vwin[ky][dx + kx], acc[dx]));      \
      }                                                                    \
      _Pragma("unroll")                                                    \
      for (int dx = 0; dx < 4; ++dx)                                       \
        outv[DY][dx] = fmaxf(outv[DY][dx], acc[dx]);                       \
    }                                                                      \
  }

// Shift both windows down one row; load plane row NEXTROW into slot 2.
#define WIN_SHIFT2(NEXTROW)                                                \
  {                                                                        \
    _Pragma("unroll")                                                      \
    for (int j = 0; j < 6; ++j) {                                          \
      rwin[0][j] = rwin[1][j]; rwin[1][j] = rwin[2][j];                    \
      vwin[0][j] = vwin[1][j]; vwin[1][j] = vwin[2][j];                    \
    }                                                                      \
    LOAD_WROW(rp, (NEXTROW), rwin[2])                                      \
    LOAD_WROW(vp, (NEXTROW), vwin[2])                                      \
  }

// One r-phase row: racc[DY][*] = b_eff + W_eff(ch0)*rwin + W_eff(ch1)*vwin.
#define R_ROW(DY)                                                          \
  {                                                                        \
    _Pragma("unroll")                                                      \
    for (int dx = 0; dx < 4; ++dx) racc[DY][dx] = beff;                    \
    _Pragma("unroll")                                                      \
    for (int kk = 0; kk < 9; ++kk) {                                       \
      const int ky = kk / 3, kx = kk % 3;                                  \
      const float w0 = w_eff[kk];                                          \
      const float w1 = w_eff[9 + kk];                                      \
      _Pragma("unroll")                                                    \
      for (int dx = 0; dx < 4; ++dx)                                       \
        racc[DY][dx] = __builtin_fmaf(w0, rwin[ky][dx + kx],               \
                       __builtin_fmaf(w1, vwin[ky][dx + kx], racc[DY][dx]));\
    }                                                                      \
  }

// One block per batch item; 1024 threads; each thread owns a 4x4 tile.
// LDS: r plane + v plane (137.3 KB) -> 1 block/CU, 16 waves (4/SIMD).
__global__ __launch_bounds__(1024)
__attribute__((amdgpu_waves_per_eu(4, 4)))
void vin_main(const float* __restrict__ input,
              const int* __restrict__ coords,
              const float* __restrict__ q_w,
              const float* __restrict__ w_in,
              const float* __restrict__ fc_w,
              const float* __restrict__ w_eff,
              float* __restrict__ out) {
  extern __shared__ float lds[];
  float* rplane = lds + RPOFF;  // stages ch0, then holds r (read-only after)
  float* vplane = lds + VPOFF;  // stages ch1, then v

  const int b = blockIdx.x;
  const int tid = threadIdx.x;
  const int ty = tid >> 5;              // 0..31
  const int tx = tid & 31;              // 0..31
  const int y0 = ty << 2;               // output rows y0..y0+3
  const int x0 = tx << 2;               // output cols x0..x0+3
  const int nb_base = y0 * LCOLS + x0;  // window base (plane row y0 = pixel y0-1)
  const int wrow0 = (y0 + 1) * LCOLS + x0;  // write base (pixel row y0)

  // zero everything (halos, pads, interiors)
  for (int i = tid; i < LDS_DWORDS; i += 1024) lds[i] = 0.0f;
  __syncthreads();

  // stage input: ch0 -> rplane interior, ch1 -> vplane interior (b128 both ways)
  const float* in0 = input + (size_t)b * (LI * HS * WSD);
  const float* in1 = in0 + HS * WSD;
  {
    const float4* in40 = (const float4*)in0;
    const float4* in41 = (const float4*)in1;
    for (int i = tid; i < HS * WSD / 4; i += 1024) {
      const int y = i >> 5, x4 = (i & 31) << 2;
      *reinterpret_cast<float4*>(rplane + (y + 1) * LCOLS + x4) = in40[i];
      *reinterpret_cast<float4*>(vplane + (y + 1) * LCOLS + x4) = in41[i];
    }
  }
  __syncthreads();

  // ---- r = conv(input, W_eff, pad=1) + b_eff  (rolling windows) ----
  {
    const float* rp = rplane + nb_base;
    const float* vp = vplane + nb_base;
    float rwin[3][6], vwin[3][6], racc[4][4];
    LOAD_WROW(rp, 0, rwin[0]) LOAD_WROW(rp, 1, rwin[1]) LOAD_WROW(rp, 2, rwin[2])
    LOAD_WROW(vp, 0, vwin[0]) LOAD_WROW(vp, 1, vwin[1]) LOAD_WROW(vp, 2, vwin[2])
    const float beff = w_eff[18];
    R_ROW(0) WIN_SHIFT2(3) R_ROW(1) WIN_SHIFT2(4) R_ROW(2) WIN_SHIFT2(5) R_ROW(3)
    __syncthreads();  // all ch0/ch1 window reads done before overwriting
    // rplane <- r, vplane <- 0 (so VI iteration 0 yields exactly v0)
    const float4 z4 = {0.0f, 0.0f, 0.0f, 0.0f};
#pragma unroll
    for (int dy = 0; dy < 4; ++dy) {
      *reinterpret_cast<float4*>(rplane + wrow0 + dy * LCOLS) =
          make_float4(racc[dy][0], racc[dy][1], racc[dy][2], racc[dy][3]);
      *reinterpret_cast<float4*>(vplane + wrow0 + dy * LCOLS) = z4;
    }
  }
  __syncthreads();

  // ---- 40 identical VI iterations (single v plane, 2 barriers each) ----
  // it=0 reads v==0 -> produces exactly v0 = max_c conv(r, q_w_c).
#pragma unroll 1
  for (int it = 0; it < KIT; ++it) {
    const float* rp = rplane + nb_base;
    const float* vp = vplane + nb_base;
    float rwin[3][6], vwin[3][6], outv[4][4];
    LOAD_WROW(rp, 0, rwin[0]) LOAD_WROW(rp, 1, rwin[1]) LOAD_WROW(rp, 2, rwin[2])
    LOAD_WROW(vp, 0, vwin[0]) LOAD_WROW(vp, 1, vwin[1]) LOAD_WROW(vp, 2, vwin[2])
    VI_ROW(0) WIN_SHIFT2(3) VI_ROW(1) WIN_SHIFT2(4) VI_ROW(2) WIN_SHIFT2(5) VI_ROW(3)
    __syncthreads();  // all v reads done
#pragma unroll
    for (int dy = 0; dy < 4; ++dy)
      *reinterpret_cast<float4*>(vplane + wrow0 + dy * LCOLS) =
          make_float4(outv[dy][0], outv[dy][1], outv[dy][2], outv[dy][3]);
    __syncthreads();  // writes visible to next iteration
  }

  // ---- epilogue: q at (sx,sy) only, then logits = fc_w @ q ----
  if (tid == 0) {
    const int sx = coords[b * 4 + 0];  // H index
    const int sy = coords[b * 4 + 1];  // W index
    // pixel (sx-1+ky, sy-1+kx) -> plane[(sx+ky)*LCOLS + (sy-1+kx)];
    // col -1 / row halos resolve to zeros by layout.
    float qv[LQ];
#pragma unroll 1
    for (int c = 0; c < LQ; ++c) {
      float s = 0.0f;
#pragma unroll
      for (int kk = 0; kk < 9; ++kk) {
        const int ky = kk / 3, kx = kk % 3;
        const int off = (sx + ky) * LCOLS + (sy - 1 + kx);
        s = __builtin_fmaf(q_w[c * 9 + kk], rplane[off],
            __builtin_fmaf(w_in[c * 9 + kk], vplane[off], s));
      }
      qv[c] = s;
    }
#pragma unroll 1
    for (int a = 0; a < AOUT; ++a) {
      float s = 0.0f;
#pragma unroll
      for (int c = 0; c < LQ; ++c)
        s = __builtin_fmaf(fc_w[a * LQ + c], qv[c], s);
      out[b * AOUT + a] = s;
    }
  }
}

extern "C" void kernel_launch(void* const* d_in, const int* in_sizes, int n_in,
                              void* d_out, int out_size, void* d_ws, size_t ws_size,
                              hipStream_t stream) {
  const float* input = (const float*)d_in[0];   // (B, 2, 128, 128)
  const int*   coords = (const int*)d_in[1];    // (B, 4)
  const float* h_w = (const float*)d_in[2];     // (150, 2, 3, 3)
  const float* h_b = (const float*)d_in[3];     // (150,)
  const float* r_w = (const float*)d_in[4];     // (1, 150, 1, 1)
  const float* q_w = (const float*)d_in[5];     // (10, 1, 3, 3)
  const float* w_in = (const float*)d_in[6];    // (10, 1, 3, 3)
  const float* fc_w = (const float*)d_in[7];    // (5, 10)
  float* out = (float*)d_out;                   // (B, 5)
  float* w_eff = (float*)d_ws;                  // 19 floats scratch

  const size_t smem = (size_t)LDS_DWORDS * sizeof(float);  // 137,312 B
  hipFuncSetAttribute(reinterpret_cast<const void*>(vin_main),
                      hipFuncAttributeMaxDynamicSharedMemorySize, (int)smem);

  prep_weff<<<1, 64, 0, stream>>>(h_w, h_b, r_w, w_eff);
  vin_main<<<NBATCH, 1024, smem, stream>>>(input, coords, q_w, w_in, fc_w, w_eff, out);
}

// Round 8
// 668.965 us; speedup vs baseline: 1.7097x; 1.4596x over previous
//
#include <hip/hip_runtime.h>

// Problem constants (from reference)
#define NBATCH 256
#define LI 2
#define LH 150
#define LQ 10
#define HS 128
#define WSD 128
#define KIT 40
#define AOUT 5

// Plane layout: 130 rows x 132 cols of dwords, pixel (y,x) -> plane[(y+1)*LCOLS + (x+1)].
// Row 0 / row 129 = zero halos; dword col 0 = left halo (pixel -1); dword cols
// 129..131 = right zero pad. With x0 = 4*tx, a thread's 6-wide window (pixel
// cols x0-1..x0+4) = dwords x0..x0+5: b128@x0 (16B aligned) + b64@x0+4 — two
// aligned ds_reads per row, and the b128 halves are exactly the even pairs
// (w0,w1)(w2,w3) needed for packed-fp32 math.
#define LCOLS 132
#define LROWS 130
#define PLANE (LROWS * LCOLS)      // 17160 dwords
#define LDS_DWORDS (2 * PLANE)     // 137,280 B

typedef float v2f __attribute__((ext_vector_type(2)));

// ---- Prep: collapse the linear hidden layer.
__global__ void prep_weff(const float* __restrict__ h_w,
                          const float* __restrict__ h_b,
                          const float* __restrict__ r_w,
                          float* __restrict__ w_eff) {
  const int t = threadIdx.x;
  if (t < 18) {
    const int i = t / 9, k = t % 9;
    double s = 0.0;
    for (int h = 0; h < LH; ++h)
      s += (double)r_w[h] * (double)h_w[(h * LI + i) * 9 + k];
    w_eff[t] = (float)s;
  } else if (t == 18) {
    double s = 0.0;
    for (int h = 0; h < LH; ++h)
      s += (double)r_w[h] * (double)h_b[h];
    w_eff[18] = (float)s;
  }
}

// SROA RULE (rounds 1-4): local arrays only ever indexed by compile-time
// literals; dy hand-unrolled. VGPR WALL (rounds 2/3/6): allocator won't give
// this kernel >64 VGPRs — live set must stay under ~62 dwords.

// Load window row R: W[0]=(w0,w1) W[1]=(w2,w3) W[2]=(w4,w5), i.e. pixel cols
// x0-1..x0+4. b128 + b64, both aligned; pairs fall out of the b128 for free.
#define LOAD_PROW(P, R, W)                                                   \
  {                                                                          \
    const float4 b_ = *reinterpret_cast<const float4*>((P) + (R) * LCOLS);   \
    const float2 c_ = *reinterpret_cast<const float2*>((P) + (R) * LCOLS + 4); \
    W[0] = (v2f){b_.x, b_.y};                                                \
    W[1] = (v2f){b_.z, b_.w};                                                \
    W[2] = (v2f){c_.x, c_.y};                                                \
  }

// One 3-tap row of a 3x3 conv on window WARR[KY] into acc pairs a0 (dx 0,1)
// and a1 (dx 2,3). kx=0,2 are packed (v_pk_fma_f32 on even pairs); kx=1 is
// the misaligned tap -> 4 scalar FMAs on pair elements (constant indices).
#define TAPROW(KY, WARR, K0, K1, K2)                                         \
    a0 = __builtin_elementwise_fma((v2f){(K0), (K0)}, WARR[KY][0], a0);      \
    a1 = __builtin_elementwise_fma((v2f){(K0), (K0)}, WARR[KY][1], a1);      \
    a0.x = __builtin_fmaf((K1), WARR[KY][0].y, a0.x);                        \
    a0.y = __builtin_fmaf((K1), WARR[KY][1].x, a0.y);                        \
    a1.x = __builtin_fmaf((K1), WARR[KY][1].y, a1.x);                        \
    a1.y = __builtin_fmaf((K1), WARR[KY][2].x, a1.y);                        \
    a0 = __builtin_elementwise_fma((v2f){(K2), (K2)}, WARR[KY][1], a0);      \
    a1 = __builtin_elementwise_fma((v2f){(K2), (K2)}, WARR[KY][2], a1);

// One channel: a = conv(r, qc) + conv(v, wc) over the current windows, then
// MERGE folds a0/a1 into o0/o1 (assign for c=0, pk-max otherwise).
#define VI_CH(QC, WC, MERGE)                                                 \
  {                                                                          \
    const float* qc = (QC);                                                  \
    const float* wc = (WC);                                                  \
    v2f a0 = (v2f){qc[0], qc[0]} * rw[0][0];                                 \
    v2f a1 = (v2f){qc[0], qc[0]} * rw[0][1];                                 \
    a0.x = __builtin_fmaf(qc[1], rw[0][0].y, a0.x);                          \
    a0.y = __builtin_fmaf(qc[1], rw[0][1].x, a0.y);                          \
    a1.x = __builtin_fmaf(qc[1], rw[0][1].y, a1.x);                          \
    a1.y = __builtin_fmaf(qc[1], rw[0][2].x, a1.y);                          \
    a0 = __builtin_elementwise_fma((v2f){qc[2], qc[2]}, rw[0][1], a0);       \
    a1 = __builtin_elementwise_fma((v2f){qc[2], qc[2]}, rw[0][2], a1);       \
    TAPROW(1, rw, qc[3], qc[4], qc[5])                                       \
    TAPROW(2, rw, qc[6], qc[7], qc[8])                                       \
    TAPROW(0, vw, wc[0], wc[1], wc[2])                                       \
    TAPROW(1, vw, wc[3], wc[4], wc[5])                                       \
    TAPROW(2, vw, wc[6], wc[7], wc[8])                                       \
    MERGE                                                                    \
  }

// One VI output row DY: c=0 seeds o (no -inf init / no fmax), c=1..9 pk-max.
#define VI_ROW(DY)                                                           \
  {                                                                          \
    v2f o0, o1;                                                              \
    VI_CH(q_w, w_in, o0 = a0; o1 = a1;)                                      \
    _Pragma("unroll 3")                                                      \
    for (int c = 1; c < LQ; ++c) {                                           \
      VI_CH(q_w + c * 9, w_in + c * 9,                                       \
            o0 = __builtin_elementwise_max(o0, a0);                          \
            o1 = __builtin_elementwise_max(o1, a1);)                         \
    }                                                                        \
    outv[DY][0] = o0; outv[DY][1] = o1;                                      \
  }

// Shift both windows down one row; load plane row NEXTROW into slot 2.
#define WIN_SHIFT2(NEXTROW)                                                  \
  {                                                                          \
    _Pragma("unroll")                                                        \
    for (int j = 0; j < 3; ++j) {                                            \
      rw[0][j] = rw[1][j]; rw[1][j] = rw[2][j];                              \
      vw[0][j] = vw[1][j]; vw[1][j] = vw[2][j];                              \
    }                                                                        \
    LOAD_PROW(rp, (NEXTROW), rw[2])                                          \
    LOAD_PROW(vp, (NEXTROW), vw[2])                                          \
  }

// One r-phase row: racc[DY] = b_eff + W_eff(ch0)*rw + W_eff(ch1)*vw.
#define R_ROW(DY)                                                            \
  {                                                                          \
    v2f a0 = (v2f){beff, beff};                                              \
    v2f a1 = a0;                                                             \
    TAPROW(0, rw, w_eff[0], w_eff[1], w_eff[2])                              \
    TAPROW(1, rw, w_eff[3], w_eff[4], w_eff[5])                              \
    TAPROW(2, rw, w_eff[6], w_eff[7], w_eff[8])                              \
    TAPROW(0, vw, w_eff[9], w_eff[10], w_eff[11])                            \
    TAPROW(1, vw, w_eff[12], w_eff[13], w_eff[14])                           \
    TAPROW(2, vw, w_eff[15], w_eff[16], w_eff[17])                           \
    racc[DY][0] = a0; racc[DY][1] = a1;                                      \
  }

// One block per batch item; 1024 threads; each thread owns a 4x4 tile.
// LDS: r plane + v plane (137,280 B) -> 1 block/CU, 16 waves (4/SIMD).
__global__ __launch_bounds__(1024)
__attribute__((amdgpu_waves_per_eu(4, 4)))
void vin_main(const float* __restrict__ input,
              const int* __restrict__ coords,
              const float* __restrict__ q_w,
              const float* __restrict__ w_in,
              const float* __restrict__ fc_w,
              const float* __restrict__ w_eff,
              float* __restrict__ out) {
  extern __shared__ float lds[];
  float* rplane = lds;          // stages ch0, then holds r (read-only after)
  float* vplane = lds + PLANE;  // stages ch1, then v

  const int b = blockIdx.x;
  const int tid = threadIdx.x;
  const int ty = tid >> 5;              // 0..31
  const int tx = tid & 31;              // 0..31
  const int y0 = ty << 2;               // output rows y0..y0+3
  const int x0 = tx << 2;               // output cols x0..x0+3
  const int nb_base = y0 * LCOLS + x0;  // window base (plane row y0, dword x0)
  const int wrow0 = (y0 + 1) * LCOLS + x0;  // write row base (dwords +1..+4)

  // zero everything (halos, pads, interiors)
  for (int i = tid; i < LDS_DWORDS; i += 1024) lds[i] = 0.0f;
  __syncthreads();

  // stage input: ch0 -> rplane interior, ch1 -> vplane interior.
  // Interior dword cols are +1-shifted -> 4 b32 LDS writes per float4.
  const float* in0 = input + (size_t)b * (LI * HS * WSD);
  const float* in1 = in0 + HS * WSD;
  {
    const float4* in40 = (const float4*)in0;
    const float4* in41 = (const float4*)in1;
    for (int i = tid; i < HS * WSD / 4; i += 1024) {
      const int y = i >> 5, x4 = (i & 31) << 2;
      const float4 a = in40[i];
      const float4 c = in41[i];
      float* r_ = rplane + (y + 1) * LCOLS + x4;
      float* v_ = vplane + (y + 1) * LCOLS + x4;
      r_[1] = a.x; r_[2] = a.y; r_[3] = a.z; r_[4] = a.w;
      v_[1] = c.x; v_[2] = c.y; v_[3] = c.z; v_[4] = c.w;
    }
  }
  __syncthreads();

  // ---- r = conv(input, W_eff, pad=1) + b_eff  (rolling windows) ----
  {
    const float* rp = rplane + nb_base;
    const float* vp = vplane + nb_base;
    v2f rw[3][3], vw[3][3], racc[4][2];
    LOAD_PROW(rp, 0, rw[0]) LOAD_PROW(rp, 1, rw[1]) LOAD_PROW(rp, 2, rw[2])
    LOAD_PROW(vp, 0, vw[0]) LOAD_PROW(vp, 1, vw[1]) LOAD_PROW(vp, 2, vw[2])
    const float beff = w_eff[18];
    R_ROW(0) WIN_SHIFT2(3) R_ROW(1) WIN_SHIFT2(4) R_ROW(2) WIN_SHIFT2(5) R_ROW(3)
    __syncthreads();  // all ch0/ch1 window reads done before overwriting
    // rplane <- r, vplane <- 0 (VI iteration 0 then yields exactly v0)
#pragma unroll
    for (int dy = 0; dy < 4; ++dy) {
      float* r_ = rplane + wrow0 + dy * LCOLS;
      float* v_ = vplane + wrow0 + dy * LCOLS;
      r_[1] = racc[dy][0].x; r_[2] = racc[dy][0].y;
      r_[3] = racc[dy][1].x; r_[4] = racc[dy][1].y;
      v_[1] = 0.0f; v_[2] = 0.0f; v_[3] = 0.0f; v_[4] = 0.0f;
    }
  }
  __syncthreads();

  // ---- 40 identical VI iterations ----
  // it=0 reads v==0 -> produces exactly v0 = max_c conv(r, q_w_c).
#pragma unroll 1
  for (int it = 0; it < KIT; ++it) {
    const float* rp = rplane + nb_base;
    const float* vp = vplane + nb_base;
    v2f rw[3][3], vw[3][3], outv[4][2];
    LOAD_PROW(rp, 0, rw[0]) LOAD_PROW(rp, 1, rw[1]) LOAD_PROW(rp, 2, rw[2])
    LOAD_PROW(vp, 0, vw[0]) LOAD_PROW(vp, 1, vw[1]) LOAD_PROW(vp, 2, vw[2])
    VI_ROW(0) WIN_SHIFT2(3) VI_ROW(1) WIN_SHIFT2(4) VI_ROW(2) WIN_SHIFT2(5) VI_ROW(3)
    __syncthreads();  // all v reads done
#pragma unroll
    for (int dy = 0; dy < 4; ++dy) {
      float* v_ = vplane + wrow0 + dy * LCOLS;
      v_[1] = outv[dy][0].x; v_[2] = outv[dy][0].y;
      v_[3] = outv[dy][1].x; v_[4] = outv[dy][1].y;
    }
    __syncthreads();  // writes visible to next iteration
  }

  // ---- epilogue: q at (sx,sy) only, then logits = fc_w @ q ----
  if (tid == 0) {
    const int sx = coords[b * 4 + 0];  // H index
    const int sy = coords[b * 4 + 1];  // W index
    // pixel (sx-1+ky, sy-1+kx) -> plane[(sx+ky)*LCOLS + (sy+kx)]; halos/pads zero.
    float qv[LQ];
#pragma unroll 1
    for (int c = 0; c < LQ; ++c) {
      float s = 0.0f;
#pragma unroll
      for (int kk = 0; kk < 9; ++kk) {
        const int ky = kk / 3, kx = kk % 3;
        const int off = (sx + ky) * LCOLS + (sy + kx);
        s = __builtin_fmaf(q_w[c * 9 + kk], rplane[off],
            __builtin_fmaf(w_in[c * 9 + kk], vplane[off], s));
      }
      qv[c] = s;
    }
#pragma unroll 1
    for (int a = 0; a < AOUT; ++a) {
      float s = 0.0f;
#pragma unroll
      for (int c = 0; c < LQ; ++c)
        s = __builtin_fmaf(fc_w[a * LQ + c], qv[c], s);
      out[b * AOUT + a] = s;
    }
  }
}

extern "C" void kernel_launch(void* const* d_in, const int* in_sizes, int n_in,
                              void* d_out, int out_size, void* d_ws, size_t ws_size,
                              hipStream_t stream) {
  const float* input = (const float*)d_in[0];   // (B, 2, 128, 128)
  const int*   coords = (const int*)d_in[1];    // (B, 4)
  const float* h_w = (const float*)d_in[2];     // (150, 2, 3, 3)
  const float* h_b = (const float*)d_in[3];     // (150,)
  const float* r_w = (const float*)d_in[4];     // (1, 150, 1, 1)
  const float* q_w = (const float*)d_in[5];     // (10, 1, 3, 3)
  const float* w_in = (const float*)d_in[6];    // (10, 1, 3, 3)
  const float* fc_w = (const float*)d_in[7];    // (5, 10)
  float* out = (float*)d_out;                   // (B, 5)
  float* w_eff = (float*)d_ws;                  // 19 floats scratch

  const size_t smem = (size_t)LDS_DWORDS * sizeof(float);  // 137,280 B
  hipFuncSetAttribute(reinterpret_cast<const void*>(vin_main),
                      hipFuncAttributeMaxDynamicSharedMemorySize, (int)smem);

  prep_weff<<<1, 64, 0, stream>>>(h_w, h_b, r_w, w_eff);
  vin_main<<<NBATCH, 1024, smem, stream>>>(input, coords, q_w, w_in, fc_w, w_eff, out);
}

// Round 9
// 654.388 us; speedup vs baseline: 1.7477x; 1.0223x over previous
//
#include <hip/hip_runtime.h>

// Problem constants (from reference)
#define NBATCH 256
#define LI 2
#define LH 150
#define LQ 10
#define HS 128
#define WSD 128
#define KIT 40
#define AOUT 5

// Plane layout: 130 rows x 132 cols of dwords, pixel (y,x) -> plane[(y+1)*LCOLS + (x+1)].
// Row 0 / row 129 = zero halos; dword col 0 = left halo; cols 129..131 = right
// zero pad. With x0 = 4*tx, a thread's 6-wide window = dwords x0..x0+5:
// b128@x0 (16B aligned) + b64@x0+4, and the b128 halves are exactly the even
// pairs (w0,w1)(w2,w3) needed for packed-fp32 math.
#define LCOLS 132
#define LROWS 130
#define PLANE (LROWS * LCOLS)      // 17160 dwords
#define LDS_DWORDS (2 * PLANE)     // 137,280 B

// d_ws layout (floats): [0..18] w_eff | [64 ..) per-block r planes
#define WSOFF_RPLANES 64
#define WS_NEED_BYTES ((size_t)(WSOFF_RPLANES + NBATCH * PLANE) * 4)

typedef float v2f __attribute__((ext_vector_type(2)));

// ---- Prep: collapse the linear hidden layer.
__global__ void prep_weff(const float* __restrict__ h_w,
                          const float* __restrict__ h_b,
                          const float* __restrict__ r_w,
                          float* __restrict__ w_eff) {
  const int t = threadIdx.x;
  if (t < 18) {
    const int i = t / 9, k = t % 9;
    double s = 0.0;
    for (int h = 0; h < LH; ++h)
      s += (double)r_w[h] * (double)h_w[(h * LI + i) * 9 + k];
    w_eff[t] = (float)s;
  } else if (t == 18) {
    double s = 0.0;
    for (int h = 0; h < LH; ++h)
      s += (double)r_w[h] * (double)h_b[h];
    w_eff[18] = (float)s;
  }
}

// SROA RULE (rounds 1-4): local arrays only ever indexed by compile-time
// literals; dy hand-unrolled. VGPR WALL (rounds 2/3/6): allocator won't give
// this kernel >64 VGPRs — live set must stay under ~62 dwords.

// Load window row R: W[0]=(w0,w1) W[1]=(w2,w3) W[2]=(w4,w5). Works for LDS
// or global pointers (b128 + b64, both 8/16B aligned).
#define LOAD_PROW(P, R, W)                                                   \
  {                                                                          \
    const float4 b_ = *reinterpret_cast<const float4*>((P) + (R) * LCOLS);   \
    const float2 c_ = *reinterpret_cast<const float2*>((P) + (R) * LCOLS + 4); \
    W[0] = (v2f){b_.x, b_.y};                                                \
    W[1] = (v2f){b_.z, b_.w};                                                \
    W[2] = (v2f){c_.x, c_.y};                                                \
  }

// One 3-tap row of a 3x3 conv on window WARR[KY] into acc pairs a0 (dx 0,1)
// and a1 (dx 2,3). kx=0,2 packed (v_pk_fma_f32); kx=1 scalar.
#define TAPROW(KY, WARR, K0, K1, K2)                                         \
    a0 = __builtin_elementwise_fma((v2f){(K0), (K0)}, WARR[KY][0], a0);      \
    a1 = __builtin_elementwise_fma((v2f){(K0), (K0)}, WARR[KY][1], a1);      \
    a0.x = __builtin_fmaf((K1), WARR[KY][0].y, a0.x);                        \
    a0.y = __builtin_fmaf((K1), WARR[KY][1].x, a0.y);                        \
    a1.x = __builtin_fmaf((K1), WARR[KY][1].y, a1.x);                        \
    a1.y = __builtin_fmaf((K1), WARR[KY][2].x, a1.y);                        \
    a0 = __builtin_elementwise_fma((v2f){(K2), (K2)}, WARR[KY][1], a0);      \
    a1 = __builtin_elementwise_fma((v2f){(K2), (K2)}, WARR[KY][2], a1);

// One channel: a = conv(r, qc) + conv(v, wc); MERGE folds a into o.
#define VI_CH(QC, WC, MERGE)                                                 \
  {                                                                          \
    const float* qc = (QC);                                                  \
    const float* wc = (WC);                                                  \
    v2f a0 = (v2f){qc[0], qc[0]} * rw[0][0];                                 \
    v2f a1 = (v2f){qc[0], qc[0]} * rw[0][1];                                 \
    a0.x = __builtin_fmaf(qc[1], rw[0][0].y, a0.x);                          \
    a0.y = __builtin_fmaf(qc[1], rw[0][1].x, a0.y);                          \
    a1.x = __builtin_fmaf(qc[1], rw[0][1].y, a1.x);                          \
    a1.y = __builtin_fmaf(qc[1], rw[0][2].x, a1.y);                          \
    a0 = __builtin_elementwise_fma((v2f){qc[2], qc[2]}, rw[0][1], a0);       \
    a1 = __builtin_elementwise_fma((v2f){qc[2], qc[2]}, rw[0][2], a1);       \
    TAPROW(1, rw, qc[3], qc[4], qc[5])                                       \
    TAPROW(2, rw, qc[6], qc[7], qc[8])                                       \
    TAPROW(0, vw, wc[0], wc[1], wc[2])                                       \
    TAPROW(1, vw, wc[3], wc[4], wc[5])                                       \
    TAPROW(2, vw, wc[6], wc[7], wc[8])                                       \
    MERGE                                                                    \
  }

// Channel sweep into o0/o1 (c=0 seeds; c=1..9 pk-max).
#define VI_CHANNELS                                                          \
    v2f o0, o1;                                                              \
    VI_CH(q_w, w_in, o0 = a0; o1 = a1;)                                      \
    _Pragma("unroll 3")                                                      \
    for (int c = 1; c < LQ; ++c) {                                           \
      VI_CH(q_w + c * 9, w_in + c * 9,                                       \
            o0 = __builtin_elementwise_max(o0, a0);                          \
            o1 = __builtin_elementwise_max(o1, a1);)                         \
    }

// Ping-pong row: compute then store immediately to the write plane (disjoint
// from the read plane -> no barrier needed before the store).
#define VI_ROW_G(DY)                                                         \
  {                                                                          \
    VI_CHANNELS                                                              \
    float* w_ = wr + (DY) * LCOLS;                                           \
    w_[1] = o0.x; w_[2] = o0.y; w_[3] = o1.x; w_[4] = o1.y;                  \
  }

// Fallback (round-8) row: accumulate into outv, stored after the barrier.
#define VI_ROW_L(DY)                                                         \
  {                                                                          \
    VI_CHANNELS                                                              \
    outv[DY][0] = o0; outv[DY][1] = o1;                                      \
  }

// Shift both windows down one row; load plane row NEXTROW into slot 2.
#define WIN_SHIFT2(NEXTROW)                                                  \
  {                                                                          \
    _Pragma("unroll")                                                        \
    for (int j = 0; j < 3; ++j) {                                            \
      rw[0][j] = rw[1][j]; rw[1][j] = rw[2][j];                              \
      vw[0][j] = vw[1][j]; vw[1][j] = vw[2][j];                              \
    }                                                                        \
    LOAD_PROW(rp, (NEXTROW), rw[2])                                          \
    LOAD_PROW(vp, (NEXTROW), vw[2])                                          \
  }

// One r-phase row: racc[DY] = b_eff + W_eff(ch0)*rw + W_eff(ch1)*vw.
#define R_ROW(DY)                                                            \
  {                                                                          \
    v2f a0 = (v2f){beff, beff};                                              \
    v2f a1 = a0;                                                             \
    TAPROW(0, rw, w_eff[0], w_eff[1], w_eff[2])                              \
    TAPROW(1, rw, w_eff[3], w_eff[4], w_eff[5])                              \
    TAPROW(2, rw, w_eff[6], w_eff[7], w_eff[8])                              \
    TAPROW(0, vw, w_eff[9], w_eff[10], w_eff[11])                            \
    TAPROW(1, vw, w_eff[12], w_eff[13], w_eff[14])                           \
    TAPROW(2, vw, w_eff[15], w_eff[16], w_eff[17])                           \
    racc[DY][0] = a0; racc[DY][1] = a1;                                      \
  }

// ---------------- Primary kernel: r in global (L2-resident), v ping-pong in
// LDS, ONE barrier per VI iteration, write-as-you-go rows. ----------------
__global__ __launch_bounds__(1024)
__attribute__((amdgpu_waves_per_eu(4, 4)))
void vin_gr(const float* __restrict__ input,
            const int* __restrict__ coords,
            const float* __restrict__ q_w,
            const float* __restrict__ w_in,
            const float* __restrict__ fc_w,
            float* __restrict__ ws,
            float* __restrict__ out) {
  extern __shared__ float lds[];
  float* pA = lds;          // stages ch0; then v ping-pong plane A
  float* pB = lds + PLANE;  // stages ch1; then v ping-pong plane B
  const float* w_eff = ws;                          // 19 floats
  float* g_r = ws + WSOFF_RPLANES + (size_t)blockIdx.x * PLANE;

  const int b = blockIdx.x;
  const int tid = threadIdx.x;
  const int ty = tid >> 5;              // 0..31
  const int tx = tid & 31;              // 0..31
  const int y0 = ty << 2;               // output rows y0..y0+3
  const int x0 = tx << 2;               // output cols x0..x0+3
  const int nb_base = y0 * LCOLS + x0;  // window base
  const int wrow0 = (y0 + 1) * LCOLS + x0;  // write row base (dwords +1..+4)

  // zero LDS planes and this block's global r plane (halos must be 0;
  // d_ws is re-poisoned to 0xAA before every timed launch)
  for (int i = tid; i < LDS_DWORDS; i += 1024) lds[i] = 0.0f;
  {
    const float4 z4 = {0.0f, 0.0f, 0.0f, 0.0f};
    float4* g4 = reinterpret_cast<float4*>(g_r);
    for (int i = tid; i < PLANE / 4; i += 1024) g4[i] = z4;
  }
  __syncthreads();

  // stage input: ch0 -> pA interior, ch1 -> pB interior (+1 dword col shift)
  const float* in0 = input + (size_t)b * (LI * HS * WSD);
  const float* in1 = in0 + HS * WSD;
  {
    const float4* in40 = (const float4*)in0;
    const float4* in41 = (const float4*)in1;
    for (int i = tid; i < HS * WSD / 4; i += 1024) {
      const int y = i >> 5, x4 = (i & 31) << 2;
      const float4 a = in40[i];
      const float4 c = in41[i];
      float* r_ = pA + (y + 1) * LCOLS + x4;
      float* v_ = pB + (y + 1) * LCOLS + x4;
      r_[1] = a.x; r_[2] = a.y; r_[3] = a.z; r_[4] = a.w;
      v_[1] = c.x; v_[2] = c.y; v_[3] = c.z; v_[4] = c.w;
    }
  }
  __syncthreads();

  // ---- r = conv(input, W_eff, pad=1) + b_eff -> global r plane ----
  {
    const float* rp = pA + nb_base;
    const float* vp = pB + nb_base;
    v2f rw[3][3], vw[3][3], racc[4][2];
    LOAD_PROW(rp, 0, rw[0]) LOAD_PROW(rp, 1, rw[1]) LOAD_PROW(rp, 2, rw[2])
    LOAD_PROW(vp, 0, vw[0]) LOAD_PROW(vp, 1, vw[1]) LOAD_PROW(vp, 2, vw[2])
    const float beff = w_eff[18];
    R_ROW(0) WIN_SHIFT2(3) R_ROW(1) WIN_SHIFT2(4) R_ROW(2) WIN_SHIFT2(5) R_ROW(3)
    __syncthreads();  // all staged-input reads done
    // g_r <- r (interior), pA <- 0 (v starts at zero; iteration 0 reads pA)
#pragma unroll
    for (int dy = 0; dy < 4; ++dy) {
      float* g_ = g_r + wrow0 + dy * LCOLS;
      float* v_ = pA + wrow0 + dy * LCOLS;
      g_[1] = racc[dy][0].x; g_[2] = racc[dy][0].y;
      g_[3] = racc[dy][1].x; g_[4] = racc[dy][1].y;
      v_[1] = 0.0f; v_[2] = 0.0f; v_[3] = 0.0f; v_[4] = 0.0f;
    }
  }
  __syncthreads();  // r visible (vmcnt drained at barrier), v=0 visible

  // ---- 40 VI iterations, ONE barrier each ----
  // it even: read pA, write pB; it odd: read pB, write pA. KIT=40 even ->
  // final v lands in pA. it=0 (v==0) yields exactly v0 = max_c conv(r,q_c).
  const float* grp = g_r + nb_base;
#pragma unroll 1
  for (int it = 0; it < KIT; ++it) {
    const float* vp = lds + ((it & 1) ? PLANE : 0) + nb_base;
    float* wr = lds + ((it & 1) ? 0 : PLANE) + wrow0;
    const float* rp = grp;  // global, L2-resident, iteration-invariant
    v2f rw[3][3], vw[3][3];
    LOAD_PROW(rp, 0, rw[0]) LOAD_PROW(rp, 1, rw[1]) LOAD_PROW(rp, 2, rw[2])
    LOAD_PROW(vp, 0, vw[0]) LOAD_PROW(vp, 1, vw[1]) LOAD_PROW(vp, 2, vw[2])
    VI_ROW_G(0) WIN_SHIFT2(3) VI_ROW_G(1) WIN_SHIFT2(4) VI_ROW_G(2) WIN_SHIFT2(5) VI_ROW_G(3)
    __syncthreads();  // writes to the write-plane visible; next iter swaps
  }

  // ---- epilogue: q at (sx,sy), logits = fc_w @ q. Final v is in pA. ----
  if (tid == 0) {
    const int sx = coords[b * 4 + 0];
    const int sy = coords[b * 4 + 1];
    float qv[LQ];
#pragma unroll 1
    for (int c = 0; c < LQ; ++c) {
      float s = 0.0f;
#pragma unroll
      for (int kk = 0; kk < 9; ++kk) {
        const int ky = kk / 3, kx = kk % 3;
        const int off = (sx + ky) * LCOLS + (sy + kx);
        s = __builtin_fmaf(q_w[c * 9 + kk], g_r[off],
            __builtin_fmaf(w_in[c * 9 + kk], pA[off], s));
      }
      qv[c] = s;
    }
#pragma unroll 1
    for (int a = 0; a < AOUT; ++a) {
      float s = 0.0f;
#pragma unroll
      for (int c = 0; c < LQ; ++c)
        s = __builtin_fmaf(fc_w[a * LQ + c], qv[c], s);
      out[b * AOUT + a] = s;
    }
  }
}

// ---------------- Fallback kernel (round-8 structure, proven 669 us):
// used only if ws_size can't hold the r planes. ----------------
__global__ __launch_bounds__(1024)
__attribute__((amdgpu_waves_per_eu(4, 4)))
void vin_lds(const float* __restrict__ input,
             const int* __restrict__ coords,
             const float* __restrict__ q_w,
             const float* __restrict__ w_in,
             const float* __restrict__ fc_w,
             const float* __restrict__ w_eff,
             float* __restrict__ out) {
  extern __shared__ float lds[];
  float* rplane = lds;
  float* vplane = lds + PLANE;

  const int b = blockIdx.x;
  const int tid = threadIdx.x;
  const int ty = tid >> 5;
  const int tx = tid & 31;
  const int y0 = ty << 2;
  const int x0 = tx << 2;
  const int nb_base = y0 * LCOLS + x0;
  const int wrow0 = (y0 + 1) * LCOLS + x0;

  for (int i = tid; i < LDS_DWORDS; i += 1024) lds[i] = 0.0f;
  __syncthreads();

  const float* in0 = input + (size_t)b * (LI * HS * WSD);
  const float* in1 = in0 + HS * WSD;
  {
    const float4* in40 = (const float4*)in0;
    const float4* in41 = (const float4*)in1;
    for (int i = tid; i < HS * WSD / 4; i += 1024) {
      const int y = i >> 5, x4 = (i & 31) << 2;
      const float4 a = in40[i];
      const float4 c = in41[i];
      float* r_ = rplane + (y + 1) * LCOLS + x4;
      float* v_ = vplane + (y + 1) * LCOLS + x4;
      r_[1] = a.x; r_[2] = a.y; r_[3] = a.z; r_[4] = a.w;
      v_[1] = c.x; v_[2] = c.y; v_[3] = c.z; v_[4] = c.w;
    }
  }
  __syncthreads();

  {
    const float* rp = rplane + nb_base;
    const float* vp = vplane + nb_base;
    v2f rw[3][3], vw[3][3], racc[4][2];
    LOAD_PROW(rp, 0, rw[0]) LOAD_PROW(rp, 1, rw[1]) LOAD_PROW(rp, 2, rw[2])
    LOAD_PROW(vp, 0, vw[0]) LOAD_PROW(vp, 1, vw[1]) LOAD_PROW(vp, 2, vw[2])
    const float beff = w_eff[18];
    R_ROW(0) WIN_SHIFT2(3) R_ROW(1) WIN_SHIFT2(4) R_ROW(2) WIN_SHIFT2(5) R_ROW(3)
    __syncthreads();
#pragma unroll
    for (int dy = 0; dy < 4; ++dy) {
      float* r_ = rplane + wrow0 + dy * LCOLS;
      float* v_ = vplane + wrow0 + dy * LCOLS;
      r_[1] = racc[dy][0].x; r_[2] = racc[dy][0].y;
      r_[3] = racc[dy][1].x; r_[4] = racc[dy][1].y;
      v_[1] = 0.0f; v_[2] = 0.0f; v_[3] = 0.0f; v_[4] = 0.0f;
    }
  }
  __syncthreads();

#pragma unroll 1
  for (int it = 0; it < KIT; ++it) {
    const float* rp = rplane + nb_base;
    const float* vp = vplane + nb_base;
    v2f rw[3][3], vw[3][3], outv[4][2];
    LOAD_PROW(rp, 0, rw[0]) LOAD_PROW(rp, 1, rw[1]) LOAD_PROW(rp, 2, rw[2])
    LOAD_PROW(vp, 0, vw[0]) LOAD_PROW(vp, 1, vw[1]) LOAD_PROW(vp, 2, vw[2])
    VI_ROW_L(0) WIN_SHIFT2(3) VI_ROW_L(1) WIN_SHIFT2(4) VI_ROW_L(2) WIN_SHIFT2(5) VI_ROW_L(3)
    __syncthreads();
#pragma unroll
    for (int dy = 0; dy < 4; ++dy) {
      float* v_ = vplane + wrow0 + dy * LCOLS;
      v_[1] = outv[dy][0].x; v_[2] = outv[dy][0].y;
      v_[3] = outv[dy][1].x; v_[4] = outv[dy][1].y;
    }
    __syncthreads();
  }

  if (tid == 0) {
    const int sx = coords[b * 4 + 0];
    const int sy = coords[b * 4 + 1];
    float qv[LQ];
#pragma unroll 1
    for (int c = 0; c < LQ; ++c) {
      float s = 0.0f;
#pragma unroll
      for (int kk = 0; kk < 9; ++kk) {
        const int ky = kk / 3, kx = kk % 3;
        const int off = (sx + ky) * LCOLS + (sy + kx);
        s = __builtin_fmaf(q_w[c * 9 + kk], rplane[off],
            __builtin_fmaf(w_in[c * 9 + kk], vplane[off], s));
      }
      qv[c] = s;
    }
#pragma unroll 1
    for (int a = 0; a < AOUT; ++a) {
      float s = 0.0f;
#pragma unroll
      for (int c = 0; c < LQ; ++c)
        s = __builtin_fmaf(fc_w[a * LQ + c], qv[c], s);
      out[b * AOUT + a] = s;
    }
  }
}

extern "C" void kernel_launch(void* const* d_in, const int* in_sizes, int n_in,
                              void* d_out, int out_size, void* d_ws, size_t ws_size,
                              hipStream_t stream) {
  const float* input = (const float*)d_in[0];   // (B, 2, 128, 128)
  const int*   coords = (const int*)d_in[1];    // (B, 4)
  const float* h_w = (const float*)d_in[2];     // (150, 2, 3, 3)
  const float* h_b = (const float*)d_in[3];     // (150,)
  const float* r_w = (const float*)d_in[4];     // (1, 150, 1, 1)
  const float* q_w = (const float*)d_in[5];     // (10, 1, 3, 3)
  const float* w_in = (const float*)d_in[6];    // (10, 1, 3, 3)
  const float* fc_w = (const float*)d_in[7];    // (5, 10)
  float* out = (float*)d_out;                   // (B, 5)
  float* ws = (float*)d_ws;

  const size_t smem = (size_t)LDS_DWORDS * sizeof(float);  // 137,280 B

  prep_weff<<<1, 64, 0, stream>>>(h_w, h_b, r_w, ws);

  if (ws_size >= WS_NEED_BYTES) {
    hipFuncSetAttribute(reinterpret_cast<const void*>(vin_gr),
                        hipFuncAttributeMaxDynamicSharedMemorySize, (int)smem);
    vin_gr<<<NBATCH, 1024, smem, stream>>>(input, coords, q_w, w_in, fc_w, ws, out);
  } else {
    hipFuncSetAttribute(reinterpret_cast<const void*>(vin_lds),
                        hipFuncAttributeMaxDynamicSharedMemorySize, (int)smem);
    vin_lds<<<NBATCH, 1024, smem, stream>>>(input, coords, q_w, w_in, fc_w, ws, out);
  }
}

// Round 10
// 642.219 us; speedup vs baseline: 1.7809x; 1.0189x over previous
//
#include <hip/hip_runtime.h>

// Problem constants (from reference)
#define NBATCH 256
#define LI 2
#define LH 150
#define LQ 10
#define HS 128
#define WSD 128
#define KIT 40
#define AOUT 5

// Plane layout: 130 rows x 132 cols of dwords, pixel (y,x) -> plane[(y+1)*LCOLS + (x+1)].
// Row 0 / row 129 = zero halos; dword col 0 = left halo; cols 129..131 = right
// zero pad. With x0 = 4*tx, a thread's 6-wide window = dwords x0..x0+5:
// b128@x0 (16B aligned) + b64@x0+4; b128 halves are the even pairs.
#define LCOLS 132
#define LROWS 130
#define PLANE (LROWS * LCOLS)      // 17160 dwords
#define LDS_DWORDS (2 * PLANE)     // 137,280 B

// d_ws layout (floats): [0..18] w_eff | [64 ..) per-block r planes
#define WSOFF_RPLANES 64
#define WS_NEED_BYTES ((size_t)(WSOFF_RPLANES + NBATCH * PLANE) * 4)

typedef float v2f __attribute__((ext_vector_type(2)));
#define SPLAT(K) ((v2f){(K), (K)})
#define FMA2(A, B, C) __builtin_elementwise_fma((A), (B), (C))

// ---- Prep: collapse the linear hidden layer.
__global__ void prep_weff(const float* __restrict__ h_w,
                          const float* __restrict__ h_b,
                          const float* __restrict__ r_w,
                          float* __restrict__ w_eff) {
  const int t = threadIdx.x;
  if (t < 18) {
    const int i = t / 9, k = t % 9;
    double s = 0.0;
    for (int h = 0; h < LH; ++h)
      s += (double)r_w[h] * (double)h_w[(h * LI + i) * 9 + k];
    w_eff[t] = (float)s;
  } else if (t == 18) {
    double s = 0.0;
    for (int h = 0; h < LH; ++h)
      s += (double)r_w[h] * (double)h_b[h];
    w_eff[18] = (float)s;
  }
}

// SROA RULE (rounds 1-4): local arrays only ever indexed by compile-time
// literals. VGPR WALL (rounds 2/3/6): live set must stay under ~62 dwords.
// VALU LAW (rounds 7-9): kernel is pure VALU-issue-bound at ~0.65x nominal
// rate (m07); only issue-count cuts move the needle.

// ---------- old-style macros (r-phase + fallback kernel) ----------
#define LOAD_PROW(P, R, W)                                                   \
  {                                                                          \
    const float4 b_ = *reinterpret_cast<const float4*>((P) + (R) * LCOLS);   \
    const float2 c_ = *reinterpret_cast<const float2*>((P) + (R) * LCOLS + 4); \
    W[0] = (v2f){b_.x, b_.y};                                                \
    W[1] = (v2f){b_.z, b_.w};                                                \
    W[2] = (v2f){c_.x, c_.y};                                                \
  }

#define TAPROW(KY, WARR, K0, K1, K2)                                         \
    a0 = FMA2(SPLAT(K0), WARR[KY][0], a0);                                   \
    a1 = FMA2(SPLAT(K0), WARR[KY][1], a1);                                   \
    a0.x = __builtin_fmaf((K1), WARR[KY][0].y, a0.x);                        \
    a0.y = __builtin_fmaf((K1), WARR[KY][1].x, a0.y);                        \
    a1.x = __builtin_fmaf((K1), WARR[KY][1].y, a1.x);                        \
    a1.y = __builtin_fmaf((K1), WARR[KY][2].x, a1.y);                        \
    a0 = FMA2(SPLAT(K2), WARR[KY][1], a0);                                   \
    a1 = FMA2(SPLAT(K2), WARR[KY][2], a1);

#define VI_CH(QC, WC, MERGE)                                                 \
  {                                                                          \
    const float* qc = (QC);                                                  \
    const float* wc = (WC);                                                  \
    v2f a0 = SPLAT(qc[0]) * rw[0][0];                                        \
    v2f a1 = SPLAT(qc[0]) * rw[0][1];                                        \
    a0.x = __builtin_fmaf(qc[1], rw[0][0].y, a0.x);                          \
    a0.y = __builtin_fmaf(qc[1], rw[0][1].x, a0.y);                          \
    a1.x = __builtin_fmaf(qc[1], rw[0][1].y, a1.x);                          \
    a1.y = __builtin_fmaf(qc[1], rw[0][2].x, a1.y);                          \
    a0 = FMA2(SPLAT(qc[2]), rw[0][1], a0);                                   \
    a1 = FMA2(SPLAT(qc[2]), rw[0][2], a1);                                   \
    TAPROW(1, rw, qc[3], qc[4], qc[5])                                       \
    TAPROW(2, rw, qc[6], qc[7], qc[8])                                       \
    TAPROW(0, vw, wc[0], wc[1], wc[2])                                       \
    TAPROW(1, vw, wc[3], wc[4], wc[5])                                       \
    TAPROW(2, vw, wc[6], wc[7], wc[8])                                       \
    MERGE                                                                    \
  }

#define VI_CHANNELS                                                          \
    v2f o0, o1;                                                              \
    VI_CH(q_w, w_in, o0 = a0; o1 = a1;)                                      \
    _Pragma("unroll 3")                                                      \
    for (int c = 1; c < LQ; ++c) {                                           \
      VI_CH(q_w + c * 9, w_in + c * 9,                                       \
            o0 = __builtin_elementwise_max(o0, a0);                          \
            o1 = __builtin_elementwise_max(o1, a1);)                         \
    }

#define VI_ROW_L(DY)                                                         \
  {                                                                          \
    VI_CHANNELS                                                              \
    outv[DY][0] = o0; outv[DY][1] = o1;                                      \
  }

#define WIN_SHIFT2(NEXTROW)                                                  \
  {                                                                          \
    _Pragma("unroll")                                                        \
    for (int j = 0; j < 3; ++j) {                                            \
      rw[0][j] = rw[1][j]; rw[1][j] = rw[2][j];                              \
      vw[0][j] = vw[1][j]; vw[1][j] = vw[2][j];                              \
    }                                                                        \
    LOAD_PROW(rp, (NEXTROW), rw[2])                                          \
    LOAD_PROW(vp, (NEXTROW), vw[2])                                          \
  }

#define R_ROW(DY)                                                            \
  {                                                                          \
    v2f a0 = SPLAT(beff);                                                    \
    v2f a1 = a0;                                                             \
    TAPROW(0, rw, w_eff[0], w_eff[1], w_eff[2])                              \
    TAPROW(1, rw, w_eff[3], w_eff[4], w_eff[5])                              \
    TAPROW(2, rw, w_eff[6], w_eff[7], w_eff[8])                              \
    TAPROW(0, vw, w_eff[9], w_eff[10], w_eff[11])                            \
    TAPROW(1, vw, w_eff[12], w_eff[13], w_eff[14])                           \
    TAPROW(2, vw, w_eff[15], w_eff[16], w_eff[17])                           \
    racc[DY][0] = a0; racc[DY][1] = a1;                                      \
  }

// ---------- new mod-3 slot machinery (VI loop of vin_gr) ----------
// r window slot: E pairs only (kx=1 taps scalar on pair components).
#define LOADR(SLOT, R)                                                       \
  {                                                                          \
    const float4 b_ = *reinterpret_cast<const float4*>(rp + (R) * LCOLS);    \
    const float2 c_ = *reinterpret_cast<const float2*>(rp + (R) * LCOLS + 4); \
    rP[SLOT][0] = (v2f){b_.x, b_.y};                                         \
    rP[SLOT][1] = (v2f){b_.z, b_.w};                                         \
    rP[SLOT][2] = (v2f){c_.x, c_.y};                                         \
  }

// v window slot: E pairs + odd pairs (built once per load, reused x10 chans).
#define LOADV(SLOT, R)                                                       \
  {                                                                          \
    const float4 b_ = *reinterpret_cast<const float4*>(vp + (R) * LCOLS);    \
    const float2 c_ = *reinterpret_cast<const float2*>(vp + (R) * LCOLS + 4); \
    vE[SLOT][0] = (v2f){b_.x, b_.y};                                         \
    vE[SLOT][1] = (v2f){b_.z, b_.w};                                         \
    vE[SLOT][2] = (v2f){c_.x, c_.y};                                         \
    vO[SLOT][0] = (v2f){b_.y, b_.z};                                         \
    vO[SLOT][1] = (v2f){b_.w, c_.x};                                         \
  }

// r tap-row on slot: 2 pk + 4 scalar + 2 pk = 8 issues.
#define TAP_R(SLOT, K0, K1, K2)                                              \
    a0 = FMA2(SPLAT(K0), rP[SLOT][0], a0);                                   \
    a1 = FMA2(SPLAT(K0), rP[SLOT][1], a1);                                   \
    a0.x = __builtin_fmaf((K1), rP[SLOT][0].y, a0.x);                        \
    a0.y = __builtin_fmaf((K1), rP[SLOT][1].x, a0.y);                        \
    a1.x = __builtin_fmaf((K1), rP[SLOT][1].y, a1.x);                        \
    a1.y = __builtin_fmaf((K1), rP[SLOT][2].x, a1.y);                        \
    a0 = FMA2(SPLAT(K2), rP[SLOT][1], a0);                                   \
    a1 = FMA2(SPLAT(K2), rP[SLOT][2], a1);

// v tap-row on slot: all-pk, 6 issues.
#define TAP_V(SLOT, K0, K1, K2)                                              \
    a0 = FMA2(SPLAT(K0), vE[SLOT][0], a0);                                   \
    a1 = FMA2(SPLAT(K0), vE[SLOT][1], a1);                                   \
    a0 = FMA2(SPLAT(K1), vO[SLOT][0], a0);                                   \
    a1 = FMA2(SPLAT(K1), vO[SLOT][1], a1);                                   \
    a0 = FMA2(SPLAT(K2), vE[SLOT][1], a0);                                   \
    a1 = FMA2(SPLAT(K2), vE[SLOT][2], a1);

// One channel on slots (SA,SB,SC) = window rows ky=0,1,2.
#define VI_CH3(QC, WC, SA, SB, SC, MERGE)                                    \
  {                                                                          \
    const float* qc = (QC);                                                  \
    const float* wc = (WC);                                                  \
    v2f a0 = SPLAT(qc[0]) * rP[SA][0];                                       \
    v2f a1 = SPLAT(qc[0]) * rP[SA][1];                                       \
    a0.x = __builtin_fmaf(qc[1], rP[SA][0].y, a0.x);                         \
    a0.y = __builtin_fmaf(qc[1], rP[SA][1].x, a0.y);                         \
    a1.x = __builtin_fmaf(qc[1], rP[SA][1].y, a1.x);                         \
    a1.y = __builtin_fmaf(qc[1], rP[SA][2].x, a1.y);                         \
    a0 = FMA2(SPLAT(qc[2]), rP[SA][1], a0);                                  \
    a1 = FMA2(SPLAT(qc[2]), rP[SA][2], a1);                                  \
    TAP_R(SB, qc[3], qc[4], qc[5])                                           \
    TAP_R(SC, qc[6], qc[7], qc[8])                                           \
    TAP_V(SA, wc[0], wc[1], wc[2])                                           \
    TAP_V(SB, wc[3], wc[4], wc[5])                                           \
    TAP_V(SC, wc[6], wc[7], wc[8])                                           \
    MERGE                                                                    \
  }

// One output row: channel sweep then immediate store (ping-pong write plane).
#define VI_OUT(DY, SA, SB, SC)                                               \
  {                                                                          \
    v2f o0, o1;                                                              \
    VI_CH3(q_w, w_in, SA, SB, SC, o0 = a0; o1 = a1;)                         \
    _Pragma("unroll 3")                                                      \
    for (int c = 1; c < LQ; ++c) {                                           \
      VI_CH3(q_w + c * 9, w_in + c * 9, SA, SB, SC,                          \
             o0 = __builtin_elementwise_max(o0, a0);                         \
             o1 = __builtin_elementwise_max(o1, a1);)                        \
    }                                                                        \
    float* w_ = wr + (DY) * LCOLS;                                           \
    w_[1] = o0.x; w_[2] = o0.y; w_[3] = o1.x; w_[4] = o1.y;                  \
  }

// ---------------- Primary kernel: r in global (L2-resident), v ping-pong in
// LDS, one barrier per VI iteration, mod-3 slot rotation (no window movs).
__global__ __launch_bounds__(1024)
__attribute__((amdgpu_waves_per_eu(4, 4)))
void vin_gr(const float* __restrict__ input,
            const int* __restrict__ coords,
            const float* __restrict__ q_w,
            const float* __restrict__ w_in,
            const float* __restrict__ fc_w,
            float* __restrict__ ws,
            float* __restrict__ out) {
  extern __shared__ float lds[];
  float* pA = lds;          // stages ch0; then v ping-pong plane A
  float* pB = lds + PLANE;  // stages ch1; then v ping-pong plane B
  const float* w_eff = ws;  // 19 floats
  float* g_r = ws + WSOFF_RPLANES + (size_t)blockIdx.x * PLANE;

  const int b = blockIdx.x;
  const int tid = threadIdx.x;
  const int ty = tid >> 5;              // 0..31
  const int tx = tid & 31;              // 0..31
  const int y0 = ty << 2;               // output rows y0..y0+3
  const int x0 = tx << 2;               // output cols x0..x0+3
  const int nb_base = y0 * LCOLS + x0;  // window base
  const int wrow0 = (y0 + 1) * LCOLS + x0;  // write row base (dwords +1..+4)

  // zero LDS planes; zero only the HALO of the global r plane (interior is
  // fully overwritten by the r-phase before any read; saves ~16 MB writes)
  for (int i = tid; i < LDS_DWORDS; i += 1024) lds[i] = 0.0f;
  if (tid < LCOLS) { g_r[tid] = 0.0f; g_r[129 * LCOLS + tid] = 0.0f; }
  if (tid >= 256 && tid < 384) {
    const int row = tid - 255;  // 1..128
    g_r[row * LCOLS + 0] = 0.0f;
    g_r[row * LCOLS + 129] = 0.0f;
    g_r[row * LCOLS + 130] = 0.0f;
    g_r[row * LCOLS + 131] = 0.0f;
  }
  __syncthreads();

  // stage input: ch0 -> pA interior, ch1 -> pB interior (+1 dword col shift)
  const float* in0 = input + (size_t)b * (LI * HS * WSD);
  const float* in1 = in0 + HS * WSD;
  {
    const float4* in40 = (const float4*)in0;
    const float4* in41 = (const float4*)in1;
    for (int i = tid; i < HS * WSD / 4; i += 1024) {
      const int y = i >> 5, x4 = (i & 31) << 2;
      const float4 a = in40[i];
      const float4 c = in41[i];
      float* r_ = pA + (y + 1) * LCOLS + x4;
      float* v_ = pB + (y + 1) * LCOLS + x4;
      r_[1] = a.x; r_[2] = a.y; r_[3] = a.z; r_[4] = a.w;
      v_[1] = c.x; v_[2] = c.y; v_[3] = c.z; v_[4] = c.w;
    }
  }
  __syncthreads();

  // ---- r = conv(input, W_eff, pad=1) + b_eff -> global r plane ----
  {
    const float* rp = pA + nb_base;
    const float* vp = pB + nb_base;
    v2f rw[3][3], vw[3][3], racc[4][2];
    LOAD_PROW(rp, 0, rw[0]) LOAD_PROW(rp, 1, rw[1]) LOAD_PROW(rp, 2, rw[2])
    LOAD_PROW(vp, 0, vw[0]) LOAD_PROW(vp, 1, vw[1]) LOAD_PROW(vp, 2, vw[2])
    const float beff = w_eff[18];
    R_ROW(0) WIN_SHIFT2(3) R_ROW(1) WIN_SHIFT2(4) R_ROW(2) WIN_SHIFT2(5) R_ROW(3)
    __syncthreads();  // all staged-input reads done
    // g_r <- r (interior), pA <- 0 (v starts at zero; iteration 0 reads pA)
#pragma unroll
    for (int dy = 0; dy < 4; ++dy) {
      float* g_ = g_r + wrow0 + dy * LCOLS;
      float* v_ = pA + wrow0 + dy * LCOLS;
      g_[1] = racc[dy][0].x; g_[2] = racc[dy][0].y;
      g_[3] = racc[dy][1].x; g_[4] = racc[dy][1].y;
      v_[1] = 0.0f; v_[2] = 0.0f; v_[3] = 0.0f; v_[4] = 0.0f;
    }
  }
  __syncthreads();  // r visible (vmcnt drained at barrier), v=0 visible

  // ---- 40 VI iterations, ONE barrier each, mod-3 slots ----
  // it even: read pA, write pB; it odd: read pB, write pA -> final v in pA.
  const float* grp = g_r + nb_base;
#pragma unroll 1
  for (int it = 0; it < KIT; ++it) {
    const float* vp = lds + ((it & 1) ? PLANE : 0) + nb_base;
    float* wr = lds + ((it & 1) ? 0 : PLANE) + wrow0;
    const float* rp = grp;  // global, L2-resident, iteration-invariant
    v2f rP[3][3], vE[3][3], vO[3][2];
    LOADR(0, 0) LOADR(1, 1) LOADR(2, 2)
    LOADV(0, 0) LOADV(1, 1) LOADV(2, 2)
    VI_OUT(0, 0, 1, 2)
    LOADR(0, 3) LOADV(0, 3)
    VI_OUT(1, 1, 2, 0)
    LOADR(1, 4) LOADV(1, 4)
    VI_OUT(2, 2, 0, 1)
    LOADR(2, 5) LOADV(2, 5)
    VI_OUT(3, 0, 1, 2)
    __syncthreads();  // write-plane visible; next iter swaps planes
  }

  // ---- epilogue: q at (sx,sy), logits = fc_w @ q. Final v is in pA. ----
  if (tid == 0) {
    const int sx = coords[b * 4 + 0];
    const int sy = coords[b * 4 + 1];
    float qv[LQ];
#pragma unroll 1
    for (int c = 0; c < LQ; ++c) {
      float s = 0.0f;
#pragma unroll
      for (int kk = 0; kk < 9; ++kk) {
        const int ky = kk / 3, kx = kk % 3;
        const int off = (sx + ky) * LCOLS + (sy + kx);
        s = __builtin_fmaf(q_w[c * 9 + kk], g_r[off],
            __builtin_fmaf(w_in[c * 9 + kk], pA[off], s));
      }
      qv[c] = s;
    }
#pragma unroll 1
    for (int a = 0; a < AOUT; ++a) {
      float s = 0.0f;
#pragma unroll
      for (int c = 0; c < LQ; ++c)
        s = __builtin_fmaf(fc_w[a * LQ + c], qv[c], s);
      out[b * AOUT + a] = s;
    }
  }
}

// ---------------- Fallback kernel (round-8 structure): used only if ws_size
// can't hold the r planes. ----------------
__global__ __launch_bounds__(1024)
__attribute__((amdgpu_waves_per_eu(4, 4)))
void vin_lds(const float* __restrict__ input,
             const int* __restrict__ coords,
             const float* __restrict__ q_w,
             const float* __restrict__ w_in,
             const float* __restrict__ fc_w,
             const float* __restrict__ w_eff,
             float* __restrict__ out) {
  extern __shared__ float lds[];
  float* rplane = lds;
  float* vplane = lds + PLANE;

  const int b = blockIdx.x;
  const int tid = threadIdx.x;
  const int ty = tid >> 5;
  const int tx = tid & 31;
  const int y0 = ty << 2;
  const int x0 = tx << 2;
  const int nb_base = y0 * LCOLS + x0;
  const int wrow0 = (y0 + 1) * LCOLS + x0;

  for (int i = tid; i < LDS_DWORDS; i += 1024) lds[i] = 0.0f;
  __syncthreads();

  const float* in0 = input + (size_t)b * (LI * HS * WSD);
  const float* in1 = in0 + HS * WSD;
  {
    const float4* in40 = (const float4*)in0;
    const float4* in41 = (const float4*)in1;
    for (int i = tid; i < HS * WSD / 4; i += 1024) {
      const int y = i >> 5, x4 = (i & 31) << 2;
      const float4 a = in40[i];
      const float4 c = in41[i];
      float* r_ = rplane + (y + 1) * LCOLS + x4;
      float* v_ = vplane + (y + 1) * LCOLS + x4;
      r_[1] = a.x; r_[2] = a.y; r_[3] = a.z; r_[4] = a.w;
      v_[1] = c.x; v_[2] = c.y; v_[3] = c.z; v_[4] = c.w;
    }
  }
  __syncthreads();

  {
    const float* rp = rplane + nb_base;
    const float* vp = vplane + nb_base;
    v2f rw[3][3], vw[3][3], racc[4][2];
    LOAD_PROW(rp, 0, rw[0]) LOAD_PROW(rp, 1, rw[1]) LOAD_PROW(rp, 2, rw[2])
    LOAD_PROW(vp, 0, vw[0]) LOAD_PROW(vp, 1, vw[1]) LOAD_PROW(vp, 2, vw[2])
    const float beff = w_eff[18];
    R_ROW(0) WIN_SHIFT2(3) R_ROW(1) WIN_SHIFT2(4) R_ROW(2) WIN_SHIFT2(5) R_ROW(3)
    __syncthreads();
#pragma unroll
    for (int dy = 0; dy < 4; ++dy) {
      float* r_ = rplane + wrow0 + dy * LCOLS;
      float* v_ = vplane + wrow0 + dy * LCOLS;
      r_[1] = racc[dy][0].x; r_[2] = racc[dy][0].y;
      r_[3] = racc[dy][1].x; r_[4] = racc[dy][1].y;
      v_[1] = 0.0f; v_[2] = 0.0f; v_[3] = 0.0f; v_[4] = 0.0f;
    }
  }
  __syncthreads();

#pragma unroll 1
  for (int it = 0; it < KIT; ++it) {
    const float* rp = rplane + nb_base;
    const float* vp = vplane + nb_base;
    v2f rw[3][3], vw[3][3], outv[4][2];
    LOAD_PROW(rp, 0, rw[0]) LOAD_PROW(rp, 1, rw[1]) LOAD_PROW(rp, 2, rw[2])
    LOAD_PROW(vp, 0, vw[0]) LOAD_PROW(vp, 1, vw[1]) LOAD_PROW(vp, 2, vw[2])
    VI_ROW_L(0) WIN_SHIFT2(3) VI_ROW_L(1) WIN_SHIFT2(4) VI_ROW_L(2) WIN_SHIFT2(5) VI_ROW_L(3)
    __syncthreads();
#pragma unroll
    for (int dy = 0; dy < 4; ++dy) {
      float* v_ = vplane + wrow0 + dy * LCOLS;
      v_[1] = outv[dy][0].x; v_[2] = outv[dy][0].y;
      v_[3] = outv[dy][1].x; v_[4] = outv[dy][1].y;
    }
    __syncthreads();
  }

  if (tid == 0) {
    const int sx = coords[b * 4 + 0];
    const int sy = coords[b * 4 + 1];
    float qv[LQ];
#pragma unroll 1
    for (int c = 0; c < LQ; ++c) {
      float s = 0.0f;
#pragma unroll
      for (int kk = 0; kk < 9; ++kk) {
        const int ky = kk / 3, kx = kk % 3;
        const int off = (sx + ky) * LCOLS + (sy + kx);
        s = __builtin_fmaf(q_w[c * 9 + kk], rplane[off],
            __builtin_fmaf(w_in[c * 9 + kk], vplane[off], s));
      }
      qv[c] = s;
    }
#pragma unroll 1
    for (int a = 0; a < AOUT; ++a) {
      float s = 0.0f;
#pragma unroll
      for (int c = 0; c < LQ; ++c)
        s = __builtin_fmaf(fc_w[a * LQ + c], qv[c], s);
      out[b * AOUT + a] = s;
    }
  }
}

extern "C" void kernel_launch(void* const* d_in, const int* in_sizes, int n_in,
                              void* d_out, int out_size, void* d_ws, size_t ws_size,
                              hipStream_t stream) {
  const float* input = (const float*)d_in[0];   // (B, 2, 128, 128)
  const int*   coords = (const int*)d_in[1];    // (B, 4)
  const float* h_w = (const float*)d_in[2];     // (150, 2, 3, 3)
  const float* h_b = (const float*)d_in[3];     // (150,)
  const float* r_w = (const float*)d_in[4];     // (1, 150, 1, 1)
  const float* q_w = (const float*)d_in[5];     // (10, 1, 3, 3)
  const float* w_in = (const float*)d_in[6];    // (10, 1, 3, 3)
  const float* fc_w = (const float*)d_in[7];    // (5, 10)
  float* out = (float*)d_out;                   // (B, 5)
  float* ws = (float*)d_ws;

  const size_t smem = (size_t)LDS_DWORDS * sizeof(float);  // 137,280 B

  prep_weff<<<1, 64, 0, stream>>>(h_w, h_b, r_w, ws);

  if (ws_size >= WS_NEED_BYTES) {
    hipFuncSetAttribute(reinterpret_cast<const void*>(vin_gr),
                        hipFuncAttributeMaxDynamicSharedMemorySize, (int)smem);
    vin_gr<<<NBATCH, 1024, smem, stream>>>(input, coords, q_w, w_in, fc_w, ws, out);
  } else {
    hipFuncSetAttribute(reinterpret_cast<const void*>(vin_lds),
                        hipFuncAttributeMaxDynamicSharedMemorySize, (int)smem);
    vin_lds<<<NBATCH, 1024, smem, stream>>>(input, coords, q_w, w_in, fc_w, ws, out);
  }
}